// Round 14
// baseline (272.125 us; speedup 1.0000x reference)
//
#include <hip/hip_runtime.h>
#include <hip/hip_bf16.h>

// GCN: conv1(512->16) + relu + conv2(16->5) + mlp(5->32->5) + log_softmax
// out[dst] = dinv[dst]*(sum hs1[src] + hs1[dst]) + b1..., hs1 = dinv*(x@W1)
// Pipeline: memset(gwp) -> binscatter(seg counting sort, self-detect layout)
//   -> k_deg(dinv) -> gemm1(MFMA, W1 packed in LDS) -> agg1s -> agg2s
// agg kernels re-sort their bucket from pairs into LDS stage (32KB) and
// aggregate from LDS: no ssrc materialization, no k_bucket.

#define F_IN 512
#define HDIM 16
#define CDIM 5
#define NB   1024      // dst-range buckets
#define SEG  8192      // per-bucket segment capacity (mean 6250, +24 sigma)
#define GWP_STRIDE 16  // pad gwp counters to one per 64B line
#define EPT  10        // edges per thread in binscatter
#define SCHUNK (1024*EPT)

typedef __attribute__((ext_vector_type(8))) short short8;
typedef __attribute__((ext_vector_type(4))) float floatx4;

__device__ inline unsigned short f2bf(float x){
  unsigned int i; __builtin_memcpy(&i, &x, 4);
  unsigned int r = i + 0x7FFFu + ((i >> 16) & 1u);
  return (unsigned short)(r >> 16);
}
__device__ inline float ulo(unsigned int u){
  unsigned int v = u << 16; float f; __builtin_memcpy(&f, &v, 4); return f;
}
__device__ inline float uhi(unsigned int u){
  unsigned int v = u & 0xFFFF0000u; float f; __builtin_memcpy(&f, &v, 4); return f;
}
__device__ inline short8 pack8(float4 u0, float4 u1){
  unsigned short o[8] = {f2bf(u0.x), f2bf(u0.y), f2bf(u0.z), f2bf(u0.w),
                         f2bf(u1.x), f2bf(u1.y), f2bf(u1.z), f2bf(u1.w)};
  short8 r; __builtin_memcpy(&r, o, 16); return r;
}

// ---- block-local counting sort, edges in regs, k->bucket LDS map, self-detect
__global__ __launch_bounds__(1024) void k_binscatter(const int* __restrict__ ei,
    int* __restrict__ gwp, int* __restrict__ pairs, int E, int NPB){
  __shared__ int bh[NB];              // hist, then local write-ptr
  __shared__ int lex[NB];             // local exclusive scan
  __shared__ int bb2[NB];             // reserved global base per bucket
  __shared__ int wsum[16];
  __shared__ int is32_s;
  __shared__ unsigned short kb[SCHUNK];  // k -> bucket map
  __shared__ int stage[SCHUNK];
  int t = threadIdx.x;
  int e0 = blockIdx.x * SCHUNK;
  int e1 = min(E, e0 + SCHUNK);
  int cnt = e1 - e0;
  if (cnt <= 0) return;
  if (t == 0) is32_s = 0;
  bh[t] = 0;
  __syncthreads();
  // self-detect: odd 32-bit words of own chunk all zero => int64 layout
  if (t < 256){
    long long e = e0 + ((long long)t * cnt) / 256;
    if (ei[2 * e + 1] != 0) atomicOr(&is32_s, 1);
  }
  __syncthreads();
  int is32 = is32_s;
  const uint2* ei2 = (const uint2*)ei;
  int pk[EPT]; int bi[EPT];
  #pragma unroll
  for (int j = 0; j < EPT; ++j){
    int e = e0 + t + j * 1024;
    if (e < e1){
      int src, dst;
      if (is32){ src = ei[e]; dst = ei[(size_t)E + e]; }
      else     { src = (int)ei2[e].x; dst = (int)ei2[(size_t)E + e].x; }
      int b = dst / NPB;
      pk[j] = src | ((dst - b * NPB) << 20);
      bi[j] = b;
    } else bi[j] = -1;
  }
  // A: local hist from regs
  #pragma unroll
  for (int j = 0; j < EPT; ++j) if (bi[j] >= 0) atomicAdd(&bh[bi[j]], 1);
  __syncthreads();
  // B: block scan (t == bucket), reserve run in bucket segment (gwp zero-based)
  {
    int lane = t & 63, w = t >> 6;
    int v = bh[t];
    int xs = v;
    #pragma unroll
    for (int off = 1; off < 64; off <<= 1){
      int y = __shfl_up(xs, off);
      if (lane >= off) xs += y;
    }
    if (lane == 63) wsum[w] = xs;
    __syncthreads();
    int woff = 0;
    for (int k = 0; k < w; ++k) woff += wsum[k];
    int excl = woff + xs - v;
    lex[t] = excl;
    bb2[t] = t * SEG + (v ? atomicAdd(&gwp[t * GWP_STRIDE], v) : 0);
    __syncthreads();              // all reads of bh done before overwrite
    bh[t] = excl;                 // becomes local write ptr
  }
  __syncthreads();
  // C: scatter into LDS stage from regs; record bucket in kb
  #pragma unroll
  for (int j = 0; j < EPT; ++j){
    if (bi[j] >= 0){
      int idx = atomicAdd(&bh[bi[j]], 1);
      stage[idx] = pk[j];
      kb[idx] = (unsigned short)bi[j];
    }
  }
  __syncthreads();
  // D: coalesced copy-out; bucket from kb (no search)
  for (int k = t; k < cnt; k += 1024){
    int b = kb[k];
    pairs[bb2[b] + (k - lex[b])] = stage[k];
  }
}

// ---- per-bucket degree -> dinv (pairs is L2/L3-hot)
__global__ __launch_bounds__(256) void k_deg(const int* __restrict__ pairs, const int* __restrict__ gwp,
                                             float* __restrict__ dinv, int n, int NPB){
  __shared__ int h[128];
  int b = blockIdx.x, t = threadIdx.x;
  int cntE = gwp[b * GWP_STRIDE];
  if (cntE < 0) cntE = 0;
  if (cntE > SEG) cntE = SEG;
  if (t < 128) h[t] = 0;
  __syncthreads();
  const int* pb = pairs + (size_t)b * SEG;
  for (int k = t; k < cntE; k += 256) atomicAdd(&h[((unsigned)pb[k]) >> 20], 1);
  __syncthreads();
  if (t < NPB){
    int node = b * NPB + t;
    if (node < n) dinv[node] = rsqrtf((float)(h[t] + 1));   // +1 self loop
  }
}

// ---- hs1 = dinv * (x @ W1) via MFMA 16x16x32 bf16; W1 packed into LDS.
__global__ __launch_bounds__(256) void k_gemm1(const float* __restrict__ x, const float* __restrict__ W1,
                                               const float* __restrict__ dinv, unsigned short* __restrict__ hs1,
                                               int n){
  __shared__ unsigned short pwl[F_IN * HDIM];   // 16KB packed B-frags
  int t = threadIdx.x;
  for (int slot = t; slot < 1024; slot += 256){
    int col = slot & 15, kg = (slot >> 4) & 3, tt = slot >> 6;
    unsigned short o[8];
    #pragma unroll
    for (int e = 0; e < 8; ++e)
      o[e] = f2bf(W1[(tt * 32 + kg * 8 + e) * HDIM + col]);
    uint4 v; __builtin_memcpy(&v, o, 16);
    *(uint4*)(pwl + (size_t)slot * 8) = v;
  }
  __syncthreads();
  int lane = t & 63;
  int col = lane & 15, kg = lane >> 4;
  int nt = (n + 15) >> 4;
  const short8* pw8 = (const short8*)pwl;
  int nw = gridDim.x * 4;
  for (int wid = blockIdx.x * 4 + (t >> 6); wid < nt; wid += nw){
    int row = wid * 16 + col;
    const float* xr = x + (size_t)min(row, n - 1) * F_IN;
    floatx4 acc = {0.f, 0.f, 0.f, 0.f};
    #pragma unroll
    for (int tt = 0; tt < 16; ++tt){
      const float4* p = (const float4*)(xr + tt * 32 + kg * 8);
      float4 u0 = p[0];
      float4 u1 = p[1];
      short8 Bf = pw8[tt * 64 + kg * 16 + col];
      acc = __builtin_amdgcn_mfma_f32_16x16x32_bf16(pack8(u0, u1), Bf, acc, 0, 0, 0);
    }
    #pragma unroll
    for (int r = 0; r < 4; ++r){
      int orow = wid * 16 + kg * 4 + r;
      if (orow < n) hs1[(size_t)orow * HDIM + col] = f2bf(dinv[orow] * acc[r]);
    }
  }
}

// ---- agg1 fused with bucket sort: block per bucket; sort pairs->LDS stage,
//      then wave-per-node gather from LDS; + b1 + relu + @W2 + dinv -> hs2
__global__ __launch_bounds__(512) void k_agg1s(const unsigned short* __restrict__ hs1,
    const int* __restrict__ pairs, const int* __restrict__ gwp,
    const float* __restrict__ dinv, const float* __restrict__ b1,
    const float* __restrict__ W2, unsigned short* __restrict__ hs2, int n, int NPB){
  __shared__ int stage[SEG];      // 32KB sorted src
  __shared__ int lcnt[4][128];
  __shared__ int tot[128];
  __shared__ int lexcl[128];
  __shared__ int w0sum;
  int b = blockIdx.x, t = threadIdx.x;
  int lane = t & 63;
  int g = t >> 7;
  int cntE = gwp[b * GWP_STRIDE];
  if (cntE < 0) cntE = 0;
  if (cntE > SEG) cntE = SEG;
  const int* pb = pairs + (size_t)b * SEG;
  lcnt[g][t & 127] = 0;
  __syncthreads();
  for (int k = t; k < cntE; k += 512)
    atomicAdd(&lcnt[g][((unsigned)pb[k]) >> 20], 1);
  __syncthreads();
  if (t < 128){
    int c = 0;
    #pragma unroll
    for (int gg = 0; gg < 4; ++gg){ int tmp = lcnt[gg][t]; lcnt[gg][t] = c; c += tmp; }
    tot[t] = c;
  }
  __syncthreads();
  {
    int v = (t < 128) ? tot[t] : 0;
    int xs = v;
    #pragma unroll
    for (int off = 1; off < 64; off <<= 1){
      int y = __shfl_up(xs, off);
      if (lane >= off) xs += y;
    }
    if (t == 63) w0sum = xs;
    __syncthreads();
    if (t < 128) lexcl[t] = xs - v + ((t >= 64) ? w0sum : 0);
  }
  __syncthreads();
  if (t < 128){
    #pragma unroll
    for (int gg = 0; gg < 4; ++gg) lcnt[gg][t] += lexcl[t];
  }
  __syncthreads();
  for (int k = t; k < cntE; k += 512){
    unsigned int v = (unsigned int)pb[k];
    int idx = atomicAdd(&lcnt[g][v >> 20], 1);
    stage[idx] = (int)(v & 0xFFFFFu);
  }
  __syncthreads();
  // aggregation: wave per node, 2 lanes/edge
  const uint4* hv = (const uint4*)hs1;
  const float4* b1v = (const float4*)b1;
  int wv = t >> 6;
  int slot = lane >> 1, half = lane & 1;
  for (int i = wv; i < NPB; i += 8){
    int node = b * NPB + i;
    if (node >= n) break;
    int beg = lexcl[i], deg = tot[i];
    float acc[8];
    #pragma unroll
    for (int k = 0; k < 8; ++k) acc[k] = 0.f;
    for (int e = beg + slot; e < beg + deg; e += 32){
      int src = stage[e];
      uint4 v = hv[(size_t)src * 2 + half];
      acc[0] += ulo(v.x); acc[1] += uhi(v.x);
      acc[2] += ulo(v.y); acc[3] += uhi(v.y);
      acc[4] += ulo(v.z); acc[5] += uhi(v.z);
      acc[6] += ulo(v.w); acc[7] += uhi(v.w);
    }
    #pragma unroll
    for (int off = 2; off < 64; off <<= 1){
      #pragma unroll
      for (int k = 0; k < 8; ++k) acc[k] += __shfl_xor(acc[k], off);
    }
    uint4 sv = hv[(size_t)node * 2 + half];
    float self[8] = {ulo(sv.x), uhi(sv.x), ulo(sv.y), uhi(sv.y),
                     ulo(sv.z), uhi(sv.z), ulo(sv.w), uhi(sv.w)};
    float dv = dinv[node];
    float4 bl = b1v[half * 2], bh = b1v[half * 2 + 1];
    float r[8];
    r[0] = fmaxf(fmaf(dv, acc[0] + self[0], bl.x), 0.f);
    r[1] = fmaxf(fmaf(dv, acc[1] + self[1], bl.y), 0.f);
    r[2] = fmaxf(fmaf(dv, acc[2] + self[2], bl.z), 0.f);
    r[3] = fmaxf(fmaf(dv, acc[3] + self[3], bl.w), 0.f);
    r[4] = fmaxf(fmaf(dv, acc[4] + self[4], bh.x), 0.f);
    r[5] = fmaxf(fmaf(dv, acc[5] + self[5], bh.y), 0.f);
    r[6] = fmaxf(fmaf(dv, acc[6] + self[6], bh.z), 0.f);
    r[7] = fmaxf(fmaf(dv, acc[7] + self[7], bh.w), 0.f);
    const float* w2 = W2 + half * 8 * CDIM;
    float p[CDIM];
    #pragma unroll
    for (int c = 0; c < CDIM; ++c){
      float s = 0.f;
      #pragma unroll
      for (int k = 0; k < 8; ++k) s = fmaf(r[k], w2[k * CDIM + c], s);
      p[c] = s;
    }
    #pragma unroll
    for (int c = 0; c < CDIM; ++c) p[c] += __shfl_xor(p[c], 1);
    if (lane == 0){
      unsigned short o[8];
      #pragma unroll
      for (int c = 0; c < CDIM; ++c) o[c] = f2bf(dv * p[c]);
      o[5] = 0; o[6] = 0; o[7] = 0;
      uint4 v; __builtin_memcpy(&v, o, 16);
      *(uint4*)(hs2 + (size_t)node * 8) = v;
    }
  }
}

// ---- agg2 fused with bucket sort: sort->LDS, wave-per-node + MLP + logsoftmax
__global__ __launch_bounds__(512) void k_agg2s(const unsigned short* __restrict__ hs2,
    const int* __restrict__ pairs, const int* __restrict__ gwp,
    const float* __restrict__ dinv, const float* __restrict__ b2,
    const float* __restrict__ W3, const float* __restrict__ b3,
    const float* __restrict__ W4, const float* __restrict__ b4,
    float* __restrict__ out, int n, int NPB){
  __shared__ int stage[SEG];
  __shared__ int lcnt[4][128];
  __shared__ int tot[128];
  __shared__ int lexcl[128];
  __shared__ int w0sum;
  int b = blockIdx.x, t = threadIdx.x;
  int lane = t & 63;
  int g = t >> 7;
  int cntE = gwp[b * GWP_STRIDE];
  if (cntE < 0) cntE = 0;
  if (cntE > SEG) cntE = SEG;
  const int* pb = pairs + (size_t)b * SEG;
  lcnt[g][t & 127] = 0;
  __syncthreads();
  for (int k = t; k < cntE; k += 512)
    atomicAdd(&lcnt[g][((unsigned)pb[k]) >> 20], 1);
  __syncthreads();
  if (t < 128){
    int c = 0;
    #pragma unroll
    for (int gg = 0; gg < 4; ++gg){ int tmp = lcnt[gg][t]; lcnt[gg][t] = c; c += tmp; }
    tot[t] = c;
  }
  __syncthreads();
  {
    int v = (t < 128) ? tot[t] : 0;
    int xs = v;
    #pragma unroll
    for (int off = 1; off < 64; off <<= 1){
      int y = __shfl_up(xs, off);
      if (lane >= off) xs += y;
    }
    if (t == 63) w0sum = xs;
    __syncthreads();
    if (t < 128) lexcl[t] = xs - v + ((t >= 64) ? w0sum : 0);
  }
  __syncthreads();
  if (t < 128){
    #pragma unroll
    for (int gg = 0; gg < 4; ++gg) lcnt[gg][t] += lexcl[t];
  }
  __syncthreads();
  for (int k = t; k < cntE; k += 512){
    unsigned int v = (unsigned int)pb[k];
    int idx = atomicAdd(&lcnt[g][v >> 20], 1);
    stage[idx] = (int)(v & 0xFFFFFu);
  }
  __syncthreads();
  const uint4* hv2 = (const uint4*)hs2;
  int wv = t >> 6;
  for (int i = wv; i < NPB; i += 8){
    int node = b * NPB + i;
    if (node >= n) break;
    int beg = lexcl[i], deg = tot[i];
    float a[CDIM];
    #pragma unroll
    for (int k = 0; k < CDIM; ++k) a[k] = 0.f;
    for (int e = beg + lane; e < beg + deg; e += 64){
      int src = stage[e];
      uint4 v = hv2[src];
      a[0] += ulo(v.x); a[1] += uhi(v.x);
      a[2] += ulo(v.y); a[3] += uhi(v.y);
      a[4] += ulo(v.z);
    }
    #pragma unroll
    for (int off = 1; off < 64; off <<= 1){
      #pragma unroll
      for (int k = 0; k < CDIM; ++k) a[k] += __shfl_xor(a[k], off);
    }
    float dv = dinv[node];
    uint4 sv = hv2[node];
    float a0 = fmaf(dv, a[0] + ulo(sv.x), b2[0]);
    float a1 = fmaf(dv, a[1] + uhi(sv.x), b2[1]);
    float a2 = fmaf(dv, a[2] + ulo(sv.y), b2[2]);
    float a3 = fmaf(dv, a[3] + uhi(sv.y), b2[3]);
    float a4 = fmaf(dv, a[4] + ulo(sv.z), b2[4]);
    int m = lane & 31;
    float h3 = b3[m];
    h3 = fmaf(a0, W3[0 * 32 + m], h3);
    h3 = fmaf(a1, W3[1 * 32 + m], h3);
    h3 = fmaf(a2, W3[2 * 32 + m], h3);
    h3 = fmaf(a3, W3[3 * 32 + m], h3);
    h3 = fmaf(a4, W3[4 * 32 + m], h3);
    h3 = fmaxf(h3, 0.f);
    float q0 = h3 * W4[m * CDIM + 0], q1 = h3 * W4[m * CDIM + 1];
    float q2 = h3 * W4[m * CDIM + 2], q3 = h3 * W4[m * CDIM + 3];
    float q4 = h3 * W4[m * CDIM + 4];
    #pragma unroll
    for (int off = 1; off < 32; off <<= 1){
      q0 += __shfl_xor(q0, off); q1 += __shfl_xor(q1, off); q2 += __shfl_xor(q2, off);
      q3 += __shfl_xor(q3, off); q4 += __shfl_xor(q4, off);
    }
    q0 += b4[0]; q1 += b4[1]; q2 += b4[2]; q3 += b4[3]; q4 += b4[4];
    float mx = fmaxf(fmaxf(fmaxf(q0, q1), fmaxf(q2, q3)), q4);
    float sum = expf(q0 - mx) + expf(q1 - mx) + expf(q2 - mx) +
                expf(q3 - mx) + expf(q4 - mx);
    float lse = mx + logf(sum);
    if (lane < CDIM){
      float v = q0;
      if (lane == 1) v = q1;
      if (lane == 2) v = q2;
      if (lane == 3) v = q3;
      if (lane == 4) v = q4;
      out[(size_t)node * CDIM + lane] = v - lse;
    }
  }
}

extern "C" void kernel_launch(void* const* d_in, const int* in_sizes, int n_in,
                              void* d_out, int out_size, void* d_ws, size_t ws_size,
                              hipStream_t stream){
  const float* x  = (const float*)d_in[0];
  const int*   ei = (const int*)d_in[1];
  const float* W1 = (const float*)d_in[2];
  const float* b1 = (const float*)d_in[3];
  const float* W2 = (const float*)d_in[4];
  const float* b2 = (const float*)d_in[5];
  const float* W3 = (const float*)d_in[6];
  const float* b3 = (const float*)d_in[7];
  const float* W4 = (const float*)d_in[8];
  const float* b4 = (const float*)d_in[9];
  float* out = (float*)d_out;

  int N = in_sizes[0] / F_IN;
  int E = in_sizes[1] / 2;
  int NPB = (N + NB - 1) / NB;      // nodes per bucket (98 for N=100000), <=128

  char* ws = (char*)d_ws;
  size_t off = 0;
  auto alloc = [&](size_t bytes) -> char* {
    char* p = ws + off;
    off += (bytes + 255) & ~(size_t)255;
    return p;
  };
  int* gwp   = (int*)alloc((size_t)NB * GWP_STRIDE * 4);
  float* dinv= (float*)alloc((size_t)N * 4);
  int* pairs = (int*)alloc((size_t)NB * SEG * 4);   // segmented, 32 MB
  unsigned short* hs1 = (unsigned short*)alloc((size_t)N * HDIM * 2);
  unsigned short* hs2 = (unsigned short*)alloc((size_t)N * 8 * 2);
  (void)ws_size; (void)n_in; (void)out_size;

  hipMemsetAsync(gwp, 0, (size_t)NB * GWP_STRIDE * 4, stream);
  int sblocks = (E + SCHUNK - 1) / SCHUNK;
  k_binscatter<<<sblocks, 1024, 0, stream>>>(ei, gwp, pairs, E, NPB);
  k_deg<<<NB, 256, 0, stream>>>(pairs, gwp, dinv, N, NPB);
  k_gemm1<<<768, 256, 0, stream>>>(x, W1, dinv, hs1, N);
  k_agg1s<<<NB, 512, 0, stream>>>(hs1, pairs, gwp, dinv, b1, W2, hs2, N, NPB);
  k_agg2s<<<NB, 512, 0, stream>>>(hs2, pairs, gwp, dinv, b2, W3, b3, W4, b4, out, N, NPB);
}

// Round 15
// 258.805 us; speedup vs baseline: 1.0515x; 1.0515x over previous
//
#include <hip/hip_runtime.h>
#include <hip/hip_bf16.h>

// GCN: conv1(512->16) + relu + conv2(16->5) + mlp(5->32->5) + log_softmax
// out[dst] = dinv[dst]*(sum hs1[src] + hs1[dst]) + b1..., hs1 = dinv*(x@W1)
// Pipeline (best-known): memset(gwp) -> binscatter(self-detect, seg counting
// sort) -> bucket(sort -> segmented ssrc + rowptr/rowdeg/dinv) -> gemm1(MFMA,
// W1 packed in own LDS) -> agg1(gather+shfl) -> agg2(gather+shfl+MLP+lsm)

#define F_IN 512
#define HDIM 16
#define CDIM 5
#define NB   1024      // dst-range buckets
#define SEG  8192      // per-bucket segment capacity (mean 6250, +24 sigma)
#define GWP_STRIDE 16  // pad gwp counters to one per 64B line
#define EPT  10        // edges per thread in binscatter
#define SCHUNK (1024*EPT)
#define CAP  8192      // per-bucket LDS staging in k_bucket (== SEG)

typedef __attribute__((ext_vector_type(8))) short short8;
typedef __attribute__((ext_vector_type(4))) float floatx4;

__device__ inline unsigned short f2bf(float x){
  unsigned int i; __builtin_memcpy(&i, &x, 4);
  unsigned int r = i + 0x7FFFu + ((i >> 16) & 1u);
  return (unsigned short)(r >> 16);
}
__device__ inline float ulo(unsigned int u){
  unsigned int v = u << 16; float f; __builtin_memcpy(&f, &v, 4); return f;
}
__device__ inline float uhi(unsigned int u){
  unsigned int v = u & 0xFFFF0000u; float f; __builtin_memcpy(&f, &v, 4); return f;
}
__device__ inline short8 pack8(float4 u0, float4 u1){
  unsigned short o[8] = {f2bf(u0.x), f2bf(u0.y), f2bf(u0.z), f2bf(u0.w),
                         f2bf(u1.x), f2bf(u1.y), f2bf(u1.z), f2bf(u1.w)};
  short8 r; __builtin_memcpy(&r, o, 16); return r;
}

// ---- block-local counting sort, edges in regs, k->bucket LDS map, self-detect
__global__ __launch_bounds__(1024) void k_binscatter(const int* __restrict__ ei,
    int* __restrict__ gwp, int* __restrict__ pairs, int E, int NPB){
  __shared__ int bh[NB];              // hist, then local write-ptr
  __shared__ int lex[NB];             // local exclusive scan
  __shared__ int bb2[NB];             // reserved global base per bucket
  __shared__ int wsum[16];
  __shared__ int is32_s;
  __shared__ unsigned short kb[SCHUNK];  // k -> bucket map
  __shared__ int stage[SCHUNK];
  int t = threadIdx.x;
  int e0 = blockIdx.x * SCHUNK;
  int e1 = min(E, e0 + SCHUNK);
  int cnt = e1 - e0;
  if (cnt <= 0) return;
  if (t == 0) is32_s = 0;
  bh[t] = 0;
  __syncthreads();
  // self-detect: odd 32-bit words of own chunk all zero => int64 layout
  if (t < 256){
    long long e = e0 + ((long long)t * cnt) / 256;
    if (ei[2 * e + 1] != 0) atomicOr(&is32_s, 1);
  }
  __syncthreads();
  int is32 = is32_s;
  const uint2* ei2 = (const uint2*)ei;
  int pk[EPT]; int bi[EPT];
  #pragma unroll
  for (int j = 0; j < EPT; ++j){
    int e = e0 + t + j * 1024;
    if (e < e1){
      int src, dst;
      if (is32){ src = ei[e]; dst = ei[(size_t)E + e]; }
      else     { src = (int)ei2[e].x; dst = (int)ei2[(size_t)E + e].x; }
      int b = dst / NPB;
      pk[j] = src | ((dst - b * NPB) << 20);
      bi[j] = b;
    } else bi[j] = -1;
  }
  // A: local hist from regs
  #pragma unroll
  for (int j = 0; j < EPT; ++j) if (bi[j] >= 0) atomicAdd(&bh[bi[j]], 1);
  __syncthreads();
  // B: block scan (t == bucket), reserve run in bucket segment (gwp zero-based)
  {
    int lane = t & 63, w = t >> 6;
    int v = bh[t];
    int xs = v;
    #pragma unroll
    for (int off = 1; off < 64; off <<= 1){
      int y = __shfl_up(xs, off);
      if (lane >= off) xs += y;
    }
    if (lane == 63) wsum[w] = xs;
    __syncthreads();
    int woff = 0;
    for (int k = 0; k < w; ++k) woff += wsum[k];
    int excl = woff + xs - v;
    lex[t] = excl;
    bb2[t] = t * SEG + (v ? atomicAdd(&gwp[t * GWP_STRIDE], v) : 0);
    __syncthreads();              // all reads of bh done before overwrite
    bh[t] = excl;                 // becomes local write ptr
  }
  __syncthreads();
  // C: scatter into LDS stage from regs; record bucket in kb
  #pragma unroll
  for (int j = 0; j < EPT; ++j){
    if (bi[j] >= 0){
      int idx = atomicAdd(&bh[bi[j]], 1);
      stage[idx] = pk[j];
      kb[idx] = (unsigned short)bi[j];
    }
  }
  __syncthreads();
  // D: coalesced copy-out; bucket from kb (no search)
  for (int k = t; k < cnt; k += 1024){
    int b = kb[k];
    pairs[bb2[b] + (k - lex[b])] = stage[k];
  }
}

// ---- per-bucket CSR finalize: 8-way sub-hist, shfl scan, LDS sort,
//      coalesced flush into SEGMENTED ssrc; emits rowptr + rowdeg + dinv.
__global__ __launch_bounds__(512) void k_bucket(const int* __restrict__ pairs, const int* __restrict__ gwp,
                                                int* __restrict__ rowptr, int* __restrict__ rowdeg,
                                                float* __restrict__ dinv, int* __restrict__ ssrc,
                                                int NPB, int n){
  __shared__ int lcnt[8][128];    // sub-hists, then sub-write-ptrs
  __shared__ int tot[128];
  __shared__ int lexcl[128];
  __shared__ int w0sum;
  __shared__ int stage[CAP];
  int b = blockIdx.x;
  int t = threadIdx.x;
  int g = t >> 6;                 // 8 groups of 64 threads
  int node0 = b * NPB;
  int pbase = b * SEG;
  int cntE = gwp[b * GWP_STRIDE];               // zero-based count
  if (cntE < 0) cntE = 0;
  if (cntE > SEG) cntE = SEG;
  for (int k = t & 63; k < 128; k += 64) lcnt[g][k] = 0;
  __syncthreads();
  for (int k = t; k < cntE; k += 512){
    unsigned int v = (unsigned int)pairs[pbase + k];
    atomicAdd(&lcnt[g][v >> 20], 1);
  }
  __syncthreads();
  if (t < 128){
    int c = 0;
    #pragma unroll
    for (int gg = 0; gg < 8; ++gg){
      int tmp = lcnt[gg][t];
      lcnt[gg][t] = c;
      c += tmp;
    }
    tot[t] = c;
  }
  __syncthreads();
  // exclusive scan over tot[0..127] (2 waves + carry)
  int lane = t & 63;
  int v = (t < 128) ? tot[t] : 0;
  int xs = v;
  #pragma unroll
  for (int off = 1; off < 64; off <<= 1){
    int y = __shfl_up(xs, off);
    if (lane >= off) xs += y;
  }
  if (t == 63) w0sum = xs;
  __syncthreads();
  if (t < 128) lexcl[t] = xs - v + ((t >= 64) ? w0sum : 0);
  __syncthreads();
  if (t < NPB){
    int node = node0 + t;
    if (node < n){
      rowptr[node] = pbase + lexcl[t];
      rowdeg[node] = tot[t];
      dinv[node] = rsqrtf((float)(tot[t] + 1));            // +1 self loop
    }
  }
  if (t < 128){
    #pragma unroll
    for (int gg = 0; gg < 8; ++gg) lcnt[gg][t] += lexcl[t];
  }
  __syncthreads();
  for (int k = t; k < cntE; k += 512){
    unsigned int v2 = (unsigned int)pairs[pbase + k];
    int idx = atomicAdd(&lcnt[g][v2 >> 20], 1);
    int src = (int)(v2 & 0xFFFFFu);
    if (idx < CAP) stage[idx] = src;
    else ssrc[pbase + idx] = src;
  }
  __syncthreads();
  int m = cntE < CAP ? cntE : CAP;
  for (int k = t; k < m; k += 512) ssrc[pbase + k] = stage[k];
}

// ---- hs1 = dinv * (x @ W1) via MFMA 16x16x32 bf16; W1 packed into own LDS.
__global__ __launch_bounds__(256) void k_gemm1(const float* __restrict__ x, const float* __restrict__ W1,
                                               const float* __restrict__ dinv, unsigned short* __restrict__ hs1,
                                               int n){
  __shared__ unsigned short pwl[F_IN * HDIM];   // 16KB packed B-frags
  int t = threadIdx.x;
  for (int slot = t; slot < 1024; slot += 256){
    int col = slot & 15, kg = (slot >> 4) & 3, tt = slot >> 6;
    unsigned short o[8];
    #pragma unroll
    for (int e = 0; e < 8; ++e)
      o[e] = f2bf(W1[(tt * 32 + kg * 8 + e) * HDIM + col]);
    uint4 v; __builtin_memcpy(&v, o, 16);
    *(uint4*)(pwl + (size_t)slot * 8) = v;
  }
  __syncthreads();
  int lane = t & 63;
  int col = lane & 15, kg = lane >> 4;
  int nt = (n + 15) >> 4;
  const short8* pw8 = (const short8*)pwl;
  int nw = gridDim.x * 4;
  for (int wid = blockIdx.x * 4 + (t >> 6); wid < nt; wid += nw){
    int row = wid * 16 + col;
    const float* xr = x + (size_t)min(row, n - 1) * F_IN;
    floatx4 acc = {0.f, 0.f, 0.f, 0.f};
    #pragma unroll
    for (int tt = 0; tt < 16; ++tt){
      const float4* p = (const float4*)(xr + tt * 32 + kg * 8);
      float4 u0 = p[0];
      float4 u1 = p[1];
      short8 Bf = pw8[tt * 64 + kg * 16 + col];
      acc = __builtin_amdgcn_mfma_f32_16x16x32_bf16(pack8(u0, u1), Bf, acc, 0, 0, 0);
    }
    #pragma unroll
    for (int r = 0; r < 4; ++r){
      int orow = wid * 16 + kg * 4 + r;
      if (orow < n) hs1[(size_t)orow * HDIM + col] = f2bf(dinv[orow] * acc[r]);
    }
  }
}

// ---- conv1 aggregate + b1 + relu + @W2 + dinv scale -> hs2 bf16 [N][8]
// wave per node; 2 lanes per edge (each lane: uint4 = 8 bf16 = half hs1 row).
__global__ __launch_bounds__(256) void k_agg1(const unsigned short* __restrict__ hs1,
    const int* __restrict__ rowptr, const int* __restrict__ rowdeg, const int* __restrict__ ssrc,
    const float* __restrict__ dinv, const float* __restrict__ b1,
    const float* __restrict__ W2, unsigned short* __restrict__ hs2, int n){
  int lane = threadIdx.x & 63;
  int i = blockIdx.x * 4 + (threadIdx.x >> 6);
  if (i >= n) return;
  int slot = lane >> 1, half = lane & 1;
  int beg = rowptr[i], end = beg + rowdeg[i];
  const uint4* hv = (const uint4*)hs1;                 // row = 2 uint4
  float acc[8];
  #pragma unroll
  for (int k = 0; k < 8; ++k) acc[k] = 0.f;
  for (int e = beg + slot; e < end; e += 32){
    int src = ssrc[e];
    uint4 v = hv[(size_t)src * 2 + half];
    acc[0] += ulo(v.x); acc[1] += uhi(v.x);
    acc[2] += ulo(v.y); acc[3] += uhi(v.y);
    acc[4] += ulo(v.z); acc[5] += uhi(v.z);
    acc[6] += ulo(v.w); acc[7] += uhi(v.w);
  }
  #pragma unroll
  for (int off = 2; off < 64; off <<= 1){
    #pragma unroll
    for (int k = 0; k < 8; ++k) acc[k] += __shfl_xor(acc[k], off);
  }
  uint4 sv = hv[(size_t)i * 2 + half];
  float self[8] = {ulo(sv.x), uhi(sv.x), ulo(sv.y), uhi(sv.y),
                   ulo(sv.z), uhi(sv.z), ulo(sv.w), uhi(sv.w)};
  float dv = dinv[i];
  const float4* b1v = (const float4*)b1;
  float4 bl = b1v[half * 2], bh = b1v[half * 2 + 1];
  float r[8];
  r[0] = fmaxf(fmaf(dv, acc[0] + self[0], bl.x), 0.f);
  r[1] = fmaxf(fmaf(dv, acc[1] + self[1], bl.y), 0.f);
  r[2] = fmaxf(fmaf(dv, acc[2] + self[2], bl.z), 0.f);
  r[3] = fmaxf(fmaf(dv, acc[3] + self[3], bl.w), 0.f);
  r[4] = fmaxf(fmaf(dv, acc[4] + self[4], bh.x), 0.f);
  r[5] = fmaxf(fmaf(dv, acc[5] + self[5], bh.y), 0.f);
  r[6] = fmaxf(fmaf(dv, acc[6] + self[6], bh.z), 0.f);
  r[7] = fmaxf(fmaf(dv, acc[7] + self[7], bh.w), 0.f);
  const float* w2 = W2 + half * 8 * CDIM;
  float p[CDIM];
  #pragma unroll
  for (int c = 0; c < CDIM; ++c){
    float s = 0.f;
    #pragma unroll
    for (int k = 0; k < 8; ++k) s = fmaf(r[k], w2[k * CDIM + c], s);
    p[c] = s;
  }
  #pragma unroll
  for (int c = 0; c < CDIM; ++c) p[c] += __shfl_xor(p[c], 1);
  if (lane == 0){
    unsigned short o[8];
    #pragma unroll
    for (int c = 0; c < CDIM; ++c) o[c] = f2bf(dv * p[c]);
    o[5] = 0; o[6] = 0; o[7] = 0;
    uint4 v; __builtin_memcpy(&v, o, 16);
    *(uint4*)(hs2 + (size_t)i * 8) = v;
  }
}

// ---- conv2 aggregate + b2 + mlp + log_softmax -> out [N][5] f32
// wave per node; 1 lane per edge (uint4 = full hs2 row).
__global__ __launch_bounds__(256) void k_agg2(const unsigned short* __restrict__ hs2,
    const int* __restrict__ rowptr, const int* __restrict__ rowdeg, const int* __restrict__ ssrc,
    const float* __restrict__ dinv, const float* __restrict__ b2,
    const float* __restrict__ W3, const float* __restrict__ b3,
    const float* __restrict__ W4, const float* __restrict__ b4,
    float* __restrict__ out, int n){
  int lane = threadIdx.x & 63;
  int i = blockIdx.x * 4 + (threadIdx.x >> 6);
  if (i >= n) return;
  int beg = rowptr[i], end = beg + rowdeg[i];
  const uint4* hv = (const uint4*)hs2;                 // row = 1 uint4
  float acc[CDIM];
  #pragma unroll
  for (int k = 0; k < CDIM; ++k) acc[k] = 0.f;
  for (int e = beg + lane; e < end; e += 64){
    int src = ssrc[e];
    uint4 v = hv[src];
    acc[0] += ulo(v.x); acc[1] += uhi(v.x);
    acc[2] += ulo(v.y); acc[3] += uhi(v.y);
    acc[4] += ulo(v.z);
  }
  #pragma unroll
  for (int off = 1; off < 64; off <<= 1){
    #pragma unroll
    for (int k = 0; k < CDIM; ++k) acc[k] += __shfl_xor(acc[k], off);
  }
  float dv = dinv[i];
  uint4 sv = hv[i];
  float a0 = fmaf(dv, acc[0] + ulo(sv.x), b2[0]);
  float a1 = fmaf(dv, acc[1] + uhi(sv.x), b2[1]);
  float a2 = fmaf(dv, acc[2] + ulo(sv.y), b2[2]);
  float a3 = fmaf(dv, acc[3] + uhi(sv.y), b2[3]);
  float a4 = fmaf(dv, acc[4] + ulo(sv.z), b2[4]);
  int m = lane & 31;
  float h3 = b3[m];
  h3 = fmaf(a0, W3[0 * 32 + m], h3);
  h3 = fmaf(a1, W3[1 * 32 + m], h3);
  h3 = fmaf(a2, W3[2 * 32 + m], h3);
  h3 = fmaf(a3, W3[3 * 32 + m], h3);
  h3 = fmaf(a4, W3[4 * 32 + m], h3);
  h3 = fmaxf(h3, 0.f);
  float q0 = h3 * W4[m * CDIM + 0], q1 = h3 * W4[m * CDIM + 1], q2 = h3 * W4[m * CDIM + 2];
  float q3 = h3 * W4[m * CDIM + 3], q4 = h3 * W4[m * CDIM + 4];
  #pragma unroll
  for (int off = 1; off < 32; off <<= 1){
    q0 += __shfl_xor(q0, off); q1 += __shfl_xor(q1, off); q2 += __shfl_xor(q2, off);
    q3 += __shfl_xor(q3, off); q4 += __shfl_xor(q4, off);
  }
  q0 += b4[0]; q1 += b4[1]; q2 += b4[2]; q3 += b4[3]; q4 += b4[4];
  float mx = fmaxf(fmaxf(fmaxf(q0, q1), fmaxf(q2, q3)), q4);
  float sum = expf(q0 - mx) + expf(q1 - mx) + expf(q2 - mx) + expf(q3 - mx) + expf(q4 - mx);
  float lse = mx + logf(sum);
  if (lane < CDIM){
    float v = q0;
    if (lane == 1) v = q1;
    if (lane == 2) v = q2;
    if (lane == 3) v = q3;
    if (lane == 4) v = q4;
    out[(size_t)i * CDIM + lane] = v - lse;
  }
}

extern "C" void kernel_launch(void* const* d_in, const int* in_sizes, int n_in,
                              void* d_out, int out_size, void* d_ws, size_t ws_size,
                              hipStream_t stream){
  const float* x  = (const float*)d_in[0];
  const int*   ei = (const int*)d_in[1];
  const float* W1 = (const float*)d_in[2];
  const float* b1 = (const float*)d_in[3];
  const float* W2 = (const float*)d_in[4];
  const float* b2 = (const float*)d_in[5];
  const float* W3 = (const float*)d_in[6];
  const float* b3 = (const float*)d_in[7];
  const float* W4 = (const float*)d_in[8];
  const float* b4 = (const float*)d_in[9];
  float* out = (float*)d_out;

  int N = in_sizes[0] / F_IN;
  int E = in_sizes[1] / 2;
  int NPB = (N + NB - 1) / NB;      // nodes per bucket (98 for N=100000), <=128

  char* ws = (char*)d_ws;
  size_t off = 0;
  auto alloc = [&](size_t bytes) -> char* {
    char* p = ws + off;
    off += (bytes + 255) & ~(size_t)255;
    return p;
  };
  int* gwp   = (int*)alloc((size_t)NB * GWP_STRIDE * 4);
  int* rowptr= (int*)alloc((size_t)N * 4);
  int* rowdeg= (int*)alloc((size_t)N * 4);
  float* dinv= (float*)alloc((size_t)N * 4);
  int* pairs = (int*)alloc((size_t)NB * SEG * 4);   // segmented, 32 MB
  int* ssrc  = (int*)alloc((size_t)NB * SEG * 4);   // segmented, 32 MB
  unsigned short* hs1 = (unsigned short*)alloc((size_t)N * HDIM * 2);
  unsigned short* hs2 = (unsigned short*)alloc((size_t)N * 8 * 2);
  (void)ws_size; (void)n_in; (void)out_size;

  hipMemsetAsync(gwp, 0, (size_t)NB * GWP_STRIDE * 4, stream);
  int sblocks = (E + SCHUNK - 1) / SCHUNK;
  k_binscatter<<<sblocks, 1024, 0, stream>>>(ei, gwp, pairs, E, NPB);
  k_bucket<<<NB, 512, 0, stream>>>(pairs, gwp, rowptr, rowdeg, dinv, ssrc, NPB, N);
  k_gemm1<<<768, 256, 0, stream>>>(x, W1, dinv, hs1, N);
  k_agg1<<<(N + 3) / 4, 256, 0, stream>>>(hs1, rowptr, rowdeg, ssrc, dinv, b1, W2, hs2, N);
  k_agg2<<<(N + 3) / 4, 256, 0, stream>>>(hs2, rowptr, rowdeg, ssrc, dinv, b2, W3, b3, W4, b4, out, N);
}

// Round 16
// 256.125 us; speedup vs baseline: 1.0625x; 1.0105x over previous
//
#include <hip/hip_runtime.h>
#include <hip/hip_bf16.h>

// GCN: conv1(512->16) + relu + conv2(16->5) + mlp(5->32->5) + log_softmax
// out[dst] = dinv[dst]*(sum hs1[src] + hs1[dst]) + b1..., hs1 = dinv*(x@W1)
// Pipeline: memset(gwp) -> binscatter(self-detect, seg counting sort; EPT=13
// so 481 blocks / 256 CU-slots = 2 fills @94% util) -> bucket(sort -> seg ssrc
// + rowptr/rowdeg/dinv) -> gemm1(MFMA, W1 packed in LDS) -> agg1 -> agg2

#define F_IN 512
#define HDIM 16
#define CDIM 5
#define NB   1024      // dst-range buckets
#define SEG  8192      // per-bucket segment capacity (mean 6250, +24 sigma)
#define GWP_STRIDE 16  // pad gwp counters to one per 64B line
#define EPT  13        // edges per thread in binscatter (LDS 92KB -> 1 block/CU)
#define SCHUNK (1024*EPT)
#define CAP  8192      // per-bucket LDS staging in k_bucket (== SEG)

typedef __attribute__((ext_vector_type(8))) short short8;
typedef __attribute__((ext_vector_type(4))) float floatx4;

__device__ inline unsigned short f2bf(float x){
  unsigned int i; __builtin_memcpy(&i, &x, 4);
  unsigned int r = i + 0x7FFFu + ((i >> 16) & 1u);
  return (unsigned short)(r >> 16);
}
__device__ inline float ulo(unsigned int u){
  unsigned int v = u << 16; float f; __builtin_memcpy(&f, &v, 4); return f;
}
__device__ inline float uhi(unsigned int u){
  unsigned int v = u & 0xFFFF0000u; float f; __builtin_memcpy(&f, &v, 4); return f;
}
__device__ inline short8 pack8(float4 u0, float4 u1){
  unsigned short o[8] = {f2bf(u0.x), f2bf(u0.y), f2bf(u0.z), f2bf(u0.w),
                         f2bf(u1.x), f2bf(u1.y), f2bf(u1.z), f2bf(u1.w)};
  short8 r; __builtin_memcpy(&r, o, 16); return r;
}

// ---- block-local counting sort, edges in regs, k->bucket LDS map, self-detect
__global__ __launch_bounds__(1024) void k_binscatter(const int* __restrict__ ei,
    int* __restrict__ gwp, int* __restrict__ pairs, int E, int NPB){
  __shared__ int bh[NB];              // hist, then local write-ptr
  __shared__ int lex[NB];             // local exclusive scan
  __shared__ int bb2[NB];             // reserved global base per bucket
  __shared__ int wsum[16];
  __shared__ int is32_s;
  __shared__ unsigned short kb[SCHUNK];  // k -> bucket map
  __shared__ int stage[SCHUNK];
  int t = threadIdx.x;
  int e0 = blockIdx.x * SCHUNK;
  int e1 = min(E, e0 + SCHUNK);
  int cnt = e1 - e0;
  if (cnt <= 0) return;
  if (t == 0) is32_s = 0;
  bh[t] = 0;
  __syncthreads();
  // self-detect: odd 32-bit words of own chunk all zero => int64 layout
  if (t < 256){
    long long e = e0 + ((long long)t * cnt) / 256;
    if (ei[2 * e + 1] != 0) atomicOr(&is32_s, 1);
  }
  __syncthreads();
  int is32 = is32_s;
  const uint2* ei2 = (const uint2*)ei;
  int pk[EPT]; int bi[EPT];
  #pragma unroll
  for (int j = 0; j < EPT; ++j){
    int e = e0 + t + j * 1024;
    if (e < e1){
      int src, dst;
      if (is32){ src = ei[e]; dst = ei[(size_t)E + e]; }
      else     { src = (int)ei2[e].x; dst = (int)ei2[(size_t)E + e].x; }
      int b = dst / NPB;
      pk[j] = src | ((dst - b * NPB) << 20);
      bi[j] = b;
    } else bi[j] = -1;
  }
  // A: local hist from regs
  #pragma unroll
  for (int j = 0; j < EPT; ++j) if (bi[j] >= 0) atomicAdd(&bh[bi[j]], 1);
  __syncthreads();
  // B: block scan (t == bucket), reserve run in bucket segment (gwp zero-based)
  {
    int lane = t & 63, w = t >> 6;
    int v = bh[t];
    int xs = v;
    #pragma unroll
    for (int off = 1; off < 64; off <<= 1){
      int y = __shfl_up(xs, off);
      if (lane >= off) xs += y;
    }
    if (lane == 63) wsum[w] = xs;
    __syncthreads();
    int woff = 0;
    for (int k = 0; k < w; ++k) woff += wsum[k];
    int excl = woff + xs - v;
    lex[t] = excl;
    bb2[t] = t * SEG + (v ? atomicAdd(&gwp[t * GWP_STRIDE], v) : 0);
    __syncthreads();              // all reads of bh done before overwrite
    bh[t] = excl;                 // becomes local write ptr
  }
  __syncthreads();
  // C: scatter into LDS stage from regs; record bucket in kb
  #pragma unroll
  for (int j = 0; j < EPT; ++j){
    if (bi[j] >= 0){
      int idx = atomicAdd(&bh[bi[j]], 1);
      stage[idx] = pk[j];
      kb[idx] = (unsigned short)bi[j];
    }
  }
  __syncthreads();
  // D: coalesced copy-out; bucket from kb (no search)
  for (int k = t; k < cnt; k += 1024){
    int b = kb[k];
    pairs[bb2[b] + (k - lex[b])] = stage[k];
  }
}

// ---- per-bucket CSR finalize: 8-way sub-hist, shfl scan, LDS sort,
//      coalesced flush into SEGMENTED ssrc; emits rowptr + rowdeg + dinv.
__global__ __launch_bounds__(512) void k_bucket(const int* __restrict__ pairs, const int* __restrict__ gwp,
                                                int* __restrict__ rowptr, int* __restrict__ rowdeg,
                                                float* __restrict__ dinv, int* __restrict__ ssrc,
                                                int NPB, int n){
  __shared__ int lcnt[8][128];    // sub-hists, then sub-write-ptrs
  __shared__ int tot[128];
  __shared__ int lexcl[128];
  __shared__ int w0sum;
  __shared__ int stage[CAP];
  int b = blockIdx.x;
  int t = threadIdx.x;
  int g = t >> 6;                 // 8 groups of 64 threads
  int node0 = b * NPB;
  int pbase = b * SEG;
  int cntE = gwp[b * GWP_STRIDE];               // zero-based count
  if (cntE < 0) cntE = 0;
  if (cntE > SEG) cntE = SEG;
  for (int k = t & 63; k < 128; k += 64) lcnt[g][k] = 0;
  __syncthreads();
  for (int k = t; k < cntE; k += 512){
    unsigned int v = (unsigned int)pairs[pbase + k];
    atomicAdd(&lcnt[g][v >> 20], 1);
  }
  __syncthreads();
  if (t < 128){
    int c = 0;
    #pragma unroll
    for (int gg = 0; gg < 8; ++gg){
      int tmp = lcnt[gg][t];
      lcnt[gg][t] = c;
      c += tmp;
    }
    tot[t] = c;
  }
  __syncthreads();
  // exclusive scan over tot[0..127] (2 waves + carry)
  int lane = t & 63;
  int v = (t < 128) ? tot[t] : 0;
  int xs = v;
  #pragma unroll
  for (int off = 1; off < 64; off <<= 1){
    int y = __shfl_up(xs, off);
    if (lane >= off) xs += y;
  }
  if (t == 63) w0sum = xs;
  __syncthreads();
  if (t < 128) lexcl[t] = xs - v + ((t >= 64) ? w0sum : 0);
  __syncthreads();
  if (t < NPB){
    int node = node0 + t;
    if (node < n){
      rowptr[node] = pbase + lexcl[t];
      rowdeg[node] = tot[t];
      dinv[node] = rsqrtf((float)(tot[t] + 1));            // +1 self loop
    }
  }
  if (t < 128){
    #pragma unroll
    for (int gg = 0; gg < 8; ++gg) lcnt[gg][t] += lexcl[t];
  }
  __syncthreads();
  for (int k = t; k < cntE; k += 512){
    unsigned int v2 = (unsigned int)pairs[pbase + k];
    int idx = atomicAdd(&lcnt[g][v2 >> 20], 1);
    int src = (int)(v2 & 0xFFFFFu);
    if (idx < CAP) stage[idx] = src;
    else ssrc[pbase + idx] = src;
  }
  __syncthreads();
  int m = cntE < CAP ? cntE : CAP;
  for (int k = t; k < m; k += 512) ssrc[pbase + k] = stage[k];
}

// ---- hs1 = dinv * (x @ W1) via MFMA 16x16x32 bf16; W1 packed into own LDS.
__global__ __launch_bounds__(256) void k_gemm1(const float* __restrict__ x, const float* __restrict__ W1,
                                               const float* __restrict__ dinv, unsigned short* __restrict__ hs1,
                                               int n){
  __shared__ unsigned short pwl[F_IN * HDIM];   // 16KB packed B-frags
  int t = threadIdx.x;
  for (int slot = t; slot < 1024; slot += 256){
    int col = slot & 15, kg = (slot >> 4) & 3, tt = slot >> 6;
    unsigned short o[8];
    #pragma unroll
    for (int e = 0; e < 8; ++e)
      o[e] = f2bf(W1[(tt * 32 + kg * 8 + e) * HDIM + col]);
    uint4 v; __builtin_memcpy(&v, o, 16);
    *(uint4*)(pwl + (size_t)slot * 8) = v;
  }
  __syncthreads();
  int lane = t & 63;
  int col = lane & 15, kg = lane >> 4;
  int nt = (n + 15) >> 4;
  const short8* pw8 = (const short8*)pwl;
  int nw = gridDim.x * 4;
  for (int wid = blockIdx.x * 4 + (t >> 6); wid < nt; wid += nw){
    int row = wid * 16 + col;
    const float* xr = x + (size_t)min(row, n - 1) * F_IN;
    floatx4 acc = {0.f, 0.f, 0.f, 0.f};
    #pragma unroll
    for (int tt = 0; tt < 16; ++tt){
      const float4* p = (const float4*)(xr + tt * 32 + kg * 8);
      float4 u0 = p[0];
      float4 u1 = p[1];
      short8 Bf = pw8[tt * 64 + kg * 16 + col];
      acc = __builtin_amdgcn_mfma_f32_16x16x32_bf16(pack8(u0, u1), Bf, acc, 0, 0, 0);
    }
    #pragma unroll
    for (int r = 0; r < 4; ++r){
      int orow = wid * 16 + kg * 4 + r;
      if (orow < n) hs1[(size_t)orow * HDIM + col] = f2bf(dinv[orow] * acc[r]);
    }
  }
}

// ---- conv1 aggregate + b1 + relu + @W2 + dinv scale -> hs2 bf16 [N][8]
// wave per node; 2 lanes per edge (each lane: uint4 = 8 bf16 = half hs1 row).
__global__ __launch_bounds__(256) void k_agg1(const unsigned short* __restrict__ hs1,
    const int* __restrict__ rowptr, const int* __restrict__ rowdeg, const int* __restrict__ ssrc,
    const float* __restrict__ dinv, const float* __restrict__ b1,
    const float* __restrict__ W2, unsigned short* __restrict__ hs2, int n){
  int lane = threadIdx.x & 63;
  int i = blockIdx.x * 4 + (threadIdx.x >> 6);
  if (i >= n) return;
  int slot = lane >> 1, half = lane & 1;
  int beg = rowptr[i], end = beg + rowdeg[i];
  const uint4* hv = (const uint4*)hs1;                 // row = 2 uint4
  float acc[8];
  #pragma unroll
  for (int k = 0; k < 8; ++k) acc[k] = 0.f;
  for (int e = beg + slot; e < end; e += 32){
    int src = ssrc[e];
    uint4 v = hv[(size_t)src * 2 + half];
    acc[0] += ulo(v.x); acc[1] += uhi(v.x);
    acc[2] += ulo(v.y); acc[3] += uhi(v.y);
    acc[4] += ulo(v.z); acc[5] += uhi(v.z);
    acc[6] += ulo(v.w); acc[7] += uhi(v.w);
  }
  #pragma unroll
  for (int off = 2; off < 64; off <<= 1){
    #pragma unroll
    for (int k = 0; k < 8; ++k) acc[k] += __shfl_xor(acc[k], off);
  }
  uint4 sv = hv[(size_t)i * 2 + half];
  float self[8] = {ulo(sv.x), uhi(sv.x), ulo(sv.y), uhi(sv.y),
                   ulo(sv.z), uhi(sv.z), ulo(sv.w), uhi(sv.w)};
  float dv = dinv[i];
  const float4* b1v = (const float4*)b1;
  float4 bl = b1v[half * 2], bh = b1v[half * 2 + 1];
  float r[8];
  r[0] = fmaxf(fmaf(dv, acc[0] + self[0], bl.x), 0.f);
  r[1] = fmaxf(fmaf(dv, acc[1] + self[1], bl.y), 0.f);
  r[2] = fmaxf(fmaf(dv, acc[2] + self[2], bl.z), 0.f);
  r[3] = fmaxf(fmaf(dv, acc[3] + self[3], bl.w), 0.f);
  r[4] = fmaxf(fmaf(dv, acc[4] + self[4], bh.x), 0.f);
  r[5] = fmaxf(fmaf(dv, acc[5] + self[5], bh.y), 0.f);
  r[6] = fmaxf(fmaf(dv, acc[6] + self[6], bh.z), 0.f);
  r[7] = fmaxf(fmaf(dv, acc[7] + self[7], bh.w), 0.f);
  const float* w2 = W2 + half * 8 * CDIM;
  float p[CDIM];
  #pragma unroll
  for (int c = 0; c < CDIM; ++c){
    float s = 0.f;
    #pragma unroll
    for (int k = 0; k < 8; ++k) s = fmaf(r[k], w2[k * CDIM + c], s);
    p[c] = s;
  }
  #pragma unroll
  for (int c = 0; c < CDIM; ++c) p[c] += __shfl_xor(p[c], 1);
  if (lane == 0){
    unsigned short o[8];
    #pragma unroll
    for (int c = 0; c < CDIM; ++c) o[c] = f2bf(dv * p[c]);
    o[5] = 0; o[6] = 0; o[7] = 0;
    uint4 v; __builtin_memcpy(&v, o, 16);
    *(uint4*)(hs2 + (size_t)i * 8) = v;
  }
}

// ---- conv2 aggregate + b2 + mlp + log_softmax -> out [N][5] f32
// wave per node; 1 lane per edge (uint4 = full hs2 row).
__global__ __launch_bounds__(256) void k_agg2(const unsigned short* __restrict__ hs2,
    const int* __restrict__ rowptr, const int* __restrict__ rowdeg, const int* __restrict__ ssrc,
    const float* __restrict__ dinv, const float* __restrict__ b2,
    const float* __restrict__ W3, const float* __restrict__ b3,
    const float* __restrict__ W4, const float* __restrict__ b4,
    float* __restrict__ out, int n){
  int lane = threadIdx.x & 63;
  int i = blockIdx.x * 4 + (threadIdx.x >> 6);
  if (i >= n) return;
  int beg = rowptr[i], end = beg + rowdeg[i];
  const uint4* hv = (const uint4*)hs2;                 // row = 1 uint4
  float acc[CDIM];
  #pragma unroll
  for (int k = 0; k < CDIM; ++k) acc[k] = 0.f;
  for (int e = beg + lane; e < end; e += 64){
    int src = ssrc[e];
    uint4 v = hv[src];
    acc[0] += ulo(v.x); acc[1] += uhi(v.x);
    acc[2] += ulo(v.y); acc[3] += uhi(v.y);
    acc[4] += ulo(v.z);
  }
  #pragma unroll
  for (int off = 1; off < 64; off <<= 1){
    #pragma unroll
    for (int k = 0; k < CDIM; ++k) acc[k] += __shfl_xor(acc[k], off);
  }
  float dv = dinv[i];
  uint4 sv = hv[i];
  float a0 = fmaf(dv, acc[0] + ulo(sv.x), b2[0]);
  float a1 = fmaf(dv, acc[1] + uhi(sv.x), b2[1]);
  float a2 = fmaf(dv, acc[2] + ulo(sv.y), b2[2]);
  float a3 = fmaf(dv, acc[3] + uhi(sv.y), b2[3]);
  float a4 = fmaf(dv, acc[4] + ulo(sv.z), b2[4]);
  int m = lane & 31;
  float h3 = b3[m];
  h3 = fmaf(a0, W3[0 * 32 + m], h3);
  h3 = fmaf(a1, W3[1 * 32 + m], h3);
  h3 = fmaf(a2, W3[2 * 32 + m], h3);
  h3 = fmaf(a3, W3[3 * 32 + m], h3);
  h3 = fmaf(a4, W3[4 * 32 + m], h3);
  h3 = fmaxf(h3, 0.f);
  float q0 = h3 * W4[m * CDIM + 0], q1 = h3 * W4[m * CDIM + 1], q2 = h3 * W4[m * CDIM + 2];
  float q3 = h3 * W4[m * CDIM + 3], q4 = h3 * W4[m * CDIM + 4];
  #pragma unroll
  for (int off = 1; off < 32; off <<= 1){
    q0 += __shfl_xor(q0, off); q1 += __shfl_xor(q1, off); q2 += __shfl_xor(q2, off);
    q3 += __shfl_xor(q3, off); q4 += __shfl_xor(q4, off);
  }
  q0 += b4[0]; q1 += b4[1]; q2 += b4[2]; q3 += b4[3]; q4 += b4[4];
  float mx = fmaxf(fmaxf(fmaxf(q0, q1), fmaxf(q2, q3)), q4);
  float sum = expf(q0 - mx) + expf(q1 - mx) + expf(q2 - mx) + expf(q3 - mx) + expf(q4 - mx);
  float lse = mx + logf(sum);
  if (lane < CDIM){
    float v = q0;
    if (lane == 1) v = q1;
    if (lane == 2) v = q2;
    if (lane == 3) v = q3;
    if (lane == 4) v = q4;
    out[(size_t)i * CDIM + lane] = v - lse;
  }
}

extern "C" void kernel_launch(void* const* d_in, const int* in_sizes, int n_in,
                              void* d_out, int out_size, void* d_ws, size_t ws_size,
                              hipStream_t stream){
  const float* x  = (const float*)d_in[0];
  const int*   ei = (const int*)d_in[1];
  const float* W1 = (const float*)d_in[2];
  const float* b1 = (const float*)d_in[3];
  const float* W2 = (const float*)d_in[4];
  const float* b2 = (const float*)d_in[5];
  const float* W3 = (const float*)d_in[6];
  const float* b3 = (const float*)d_in[7];
  const float* W4 = (const float*)d_in[8];
  const float* b4 = (const float*)d_in[9];
  float* out = (float*)d_out;

  int N = in_sizes[0] / F_IN;
  int E = in_sizes[1] / 2;
  int NPB = (N + NB - 1) / NB;      // nodes per bucket (98 for N=100000), <=128

  char* ws = (char*)d_ws;
  size_t off = 0;
  auto alloc = [&](size_t bytes) -> char* {
    char* p = ws + off;
    off += (bytes + 255) & ~(size_t)255;
    return p;
  };
  int* gwp   = (int*)alloc((size_t)NB * GWP_STRIDE * 4);
  int* rowptr= (int*)alloc((size_t)N * 4);
  int* rowdeg= (int*)alloc((size_t)N * 4);
  float* dinv= (float*)alloc((size_t)N * 4);
  int* pairs = (int*)alloc((size_t)NB * SEG * 4);   // segmented, 32 MB
  int* ssrc  = (int*)alloc((size_t)NB * SEG * 4);   // segmented, 32 MB
  unsigned short* hs1 = (unsigned short*)alloc((size_t)N * HDIM * 2);
  unsigned short* hs2 = (unsigned short*)alloc((size_t)N * 8 * 2);
  (void)ws_size; (void)n_in; (void)out_size;

  hipMemsetAsync(gwp, 0, (size_t)NB * GWP_STRIDE * 4, stream);
  int sblocks = (E + SCHUNK - 1) / SCHUNK;
  k_binscatter<<<sblocks, 1024, 0, stream>>>(ei, gwp, pairs, E, NPB);
  k_bucket<<<NB, 512, 0, stream>>>(pairs, gwp, rowptr, rowdeg, dinv, ssrc, NPB, N);
  k_gemm1<<<768, 256, 0, stream>>>(x, W1, dinv, hs1, N);
  k_agg1<<<(N + 3) / 4, 256, 0, stream>>>(hs1, rowptr, rowdeg, ssrc, dinv, b1, W2, hs2, N);
  k_agg2<<<(N + 3) / 4, 256, 0, stream>>>(hs2, rowptr, rowdeg, ssrc, dinv, b2, W3, b3, W4, b4, out, N);
}